// Round 3
// baseline (717.823 us; speedup 1.0000x reference)
//
#include <hip/hip_runtime.h>
#include <math.h>

#define N_NODES 100000
#define D_IN 256
#define H1 16
#define H2 32
#define BSHIFT 7            // 128 rows per bucket
#define NB 782              // ceil(N_NODES / 128)
#define CH 8192             // edges per scatter block
#define HIST_BLOCKS 160

// ---------- bf16 helpers (manual, RNE) ----------
static __device__ __forceinline__ float bf_lo(unsigned int u) {
    return __uint_as_float(u << 16);
}
static __device__ __forceinline__ float bf_hi(unsigned int u) {
    return __uint_as_float(u & 0xffff0000u);
}
static __device__ __forceinline__ unsigned int f2bf_rne(float f) {
    unsigned int u = __float_as_uint(f);
    return (u + 0x7fffu + ((u >> 16) & 1u)) >> 16;
}
static __device__ __forceinline__ unsigned int pack_bf16(float lo, float hi) {
    return f2bf_rne(lo) | (f2bf_rne(hi) << 16);
}
static __device__ __forceinline__ unsigned int cvt_pk_bf16(float lo, float hi) {
    unsigned int r;
    asm("v_cvt_pk_bf16_f32 %0, %1, %2" : "=v"(r) : "v"(lo), "v"(hi));
    return r;
}

typedef __attribute__((ext_vector_type(8))) short bf16x8;
typedef __attribute__((ext_vector_type(4))) float f32x4;
union ABFrag { unsigned int u[4]; bf16x8 v; };

// ---------------- zero workspace region ----------------
__global__ void k_zero(float4* __restrict__ p, int n4) {
    int i = blockIdx.x * blockDim.x + threadIdx.x;
    if (i < n4) p[i] = make_float4(0.f, 0.f, 0.f, 0.f);
}

// ---------------- t = bf16(x @ W1) via MFMA 16x16x32 bf16 ----------------
#define XW1_TILES 2
#define XW1_ROWS (4 * XW1_TILES * 16)   // 128 rows per 256-thread block
__global__ __launch_bounds__(256) void k_xw1(const float* __restrict__ x,
                                             const float* __restrict__ W1,
                                             unsigned short* __restrict__ t,
                                             int n_nodes) {
    const int lane = threadIdx.x & 63;
    const int wid  = threadIdx.x >> 6;
    const int fcol = lane & 15;
    const int kgrp = lane >> 4;

    ABFrag bfrag[8];
#pragma unroll
    for (int g = 0; g < 8; g++) {
        const float* wp = W1 + (g * 32 + kgrp * 8) * H1 + fcol;
#pragma unroll
        for (int p = 0; p < 4; p++)
            bfrag[g].u[p] = cvt_pk_bf16(wp[(2 * p) * H1], wp[(2 * p + 1) * H1]);
    }

    const int wrow0 = blockIdx.x * XW1_ROWS + wid * (XW1_TILES * 16);
#pragma unroll
    for (int tile = 0; tile < XW1_TILES; tile++) {
        const int row0 = wrow0 + tile * 16;
        int arow = row0 + fcol;
        if (arow >= n_nodes) arow = n_nodes - 1;
        const float* xr = x + (size_t)arow * D_IN;
        f32x4 acc = {0.f, 0.f, 0.f, 0.f};
#pragma unroll
        for (int g = 0; g < 8; g++) {
            const float4 a0 = *(const float4*)(xr + g * 32 + kgrp * 8);
            const float4 a1 = *(const float4*)(xr + g * 32 + kgrp * 8 + 4);
            ABFrag af;
            af.u[0] = cvt_pk_bf16(a0.x, a0.y);
            af.u[1] = cvt_pk_bf16(a0.z, a0.w);
            af.u[2] = cvt_pk_bf16(a1.x, a1.y);
            af.u[3] = cvt_pk_bf16(a1.z, a1.w);
            acc = __builtin_amdgcn_mfma_f32_16x16x32_bf16(af.v, bfrag[g].v, acc, 0, 0, 0);
        }
#pragma unroll
        for (int r = 0; r < 4; r++) {
            int orow = row0 + kgrp * 4 + r;
            if (orow < n_nodes)
                t[(size_t)orow * H1 + fcol] = (unsigned short)f2bf_rne(acc[r]);
        }
    }
}

// ---------------- binning: histogram of row buckets ----------------
__global__ __launch_bounds__(256) void k_hist(const int* __restrict__ rows,
                                              int* __restrict__ hist, int E) {
    __shared__ int lh[NB];
    int tid = threadIdx.x;
    for (int b = tid; b < NB; b += 256) lh[b] = 0;
    __syncthreads();
    int stride = gridDim.x * 256;
    for (int i = blockIdx.x * 256 + tid; i < E; i += stride)
        atomicAdd(&lh[rows[i] >> BSHIFT], 1);
    __syncthreads();
    for (int b = tid; b < NB; b += 256) {
        int c = lh[b];
        if (c) atomicAdd(&hist[b], c);
    }
}

// ---------------- exclusive scan of hist -> base, init cursors ----------
__global__ __launch_bounds__(1024) void k_scan(const int* __restrict__ hist,
                                               int* __restrict__ base,
                                               unsigned int* __restrict__ cursor) {
    __shared__ int sa[1024], sb[1024];
    int tid = threadIdx.x;
    int h0 = (tid < NB) ? hist[tid] : 0;
    sa[tid] = h0;
    __syncthreads();
    int* src = sa; int* dst = sb;
    for (int off = 1; off < 1024; off <<= 1) {
        int v = src[tid];
        if (tid >= off) v += src[tid - off];
        dst[tid] = v;
        __syncthreads();
        int* tmp = src; src = dst; dst = tmp;
    }
    int incl = src[tid];
    if (tid < NB) {
        int excl = incl - h0;
        base[tid] = excl;
        cursor[tid * 16] = (unsigned int)excl;   // cursors padded to 64B lines
    }
    if (tid == NB - 1) base[NB] = incl;
}

// ---------------- scatter edges into bucket lists (8B packed) ----------
__global__ __launch_bounds__(256) void k_scatter(const int* __restrict__ rows,
                                                 const int* __restrict__ cols,
                                                 const float* __restrict__ vals,
                                                 unsigned int* __restrict__ cursor,
                                                 uint2* __restrict__ ed, int E) {
    __shared__ int lcount[NB];
    __shared__ int lbase[NB];
    int tid = threadIdx.x;
    int c0 = blockIdx.x * CH;
    int cend = min(c0 + CH, E);
    for (int b = tid; b < NB; b += 256) lcount[b] = 0;
    __syncthreads();
    for (int i = c0 + tid; i < cend; i += 256)
        atomicAdd(&lcount[rows[i] >> BSHIFT], 1);
    __syncthreads();
    for (int b = tid; b < NB; b += 256) {
        int cnt = lcount[b];
        lbase[b] = cnt ? (int)atomicAdd(&cursor[b * 16], (unsigned int)cnt) : 0;
        lcount[b] = 0;
    }
    __syncthreads();
    for (int i = c0 + tid; i < cend; i += 256) {
        int r = rows[i];
        int b = r >> BSHIFT;
        int rank = atomicAdd(&lcount[b], 1);
        int pos = lbase[b] + rank;
        ed[pos] = make_uint2(((unsigned int)cols[i] << BSHIFT) | (unsigned int)(r & 127),
                             __float_as_uint(vals[i]));
    }
}

// ---------------- per-bucket g accumulation in LDS (no global atomics) ----
__global__ __launch_bounds__(256) void k_gacc(const uint2* __restrict__ ed,
                                              const int* __restrict__ base,
                                              const unsigned short* __restrict__ t,
                                              unsigned int* __restrict__ g2,
                                              int n_nodes) {
    __shared__ float gs[128 * H1];   // 8 KB f32 slice
    int tid = threadIdx.x;
    int b = blockIdx.x;
    for (int i = tid; i < 128 * H1; i += 256) gs[i] = 0.f;
    __syncthreads();
    int e0 = base[b], e1 = base[b + 1];
    int f = tid & 15, grp = tid >> 4;
    for (int i = e0 + grp; i < e1; i += 16) {
        uint2 e = ed[i];
        int c = (int)(e.x >> BSHIFT);
        int r7 = (int)(e.x & 127);
        float v = __uint_as_float(e.y);
        float tv = __uint_as_float((unsigned int)t[c * H1 + f] << 16);
        atomicAdd(&gs[r7 * H1 + f], v * tv);   // LDS ds_add_f32, <=2-way banks
    }
    __syncthreads();
    int row0 = b << BSHIFT;
    for (int j = tid; j < 128 * H1 / 2; j += 256) {   // 1024 packed u32
        int row = j >> 3, fp = j & 7;
        int grow = row0 + row;
        if (grow < n_nodes)
            g2[grow * 8 + fp] = pack_bf16(gs[row * H1 + 2 * fp],
                                          gs[row * H1 + 2 * fp + 1]);
    }
}

// ---------------- fallback edge pass (atomic path, if ws too small) -------
__global__ __launch_bounds__(256) void k_edge(const int* __restrict__ rows,
                                              const int* __restrict__ cols,
                                              const float* __restrict__ vals,
                                              const unsigned int* __restrict__ tb,
                                              unsigned int* __restrict__ g2, int E) {
    int tid = blockIdx.x * 256 + threadIdx.x;
    int e = tid >> 3;
    int f2 = tid & 7;
    if (e >= E) return;
    int r = rows[e];
    int c = cols[e];
    float v = vals[e];
    unsigned int tv = tb[c * 8 + f2];
    unsigned int pk = pack_bf16(v * bf_lo(tv), v * bf_hi(tv));
    unsigned int* addr = g2 + (r * 8 + f2);
    asm volatile("global_atomic_pk_add_bf16 %0, %1, off"
                 :: "v"(addr), "v"(pk) : "memory");
}

// ---------------- s[f] = sum_e val[e] * relu(g[col[e]])[f] ----------------
__global__ __launch_bounds__(256) void k_s2(const int* __restrict__ cols,
                                            const float* __restrict__ vals,
                                            const unsigned int* __restrict__ g2,
                                            float* __restrict__ s, int E) {
    const int f2 = threadIdx.x & 7;
    int idx    = (blockIdx.x * 256 + threadIdx.x) >> 3;
    int stride = (gridDim.x * 256) >> 3;
    float accl = 0.f, acch = 0.f;
    for (int e = idx; e < E; e += stride) {
        int c = cols[e];
        float v = vals[e];
        unsigned int gv = g2[c * 8 + f2];
        accl = fmaf(v, fmaxf(bf_lo(gv), 0.f), accl);
        acch = fmaf(v, fmaxf(bf_hi(gv), 0.f), acch);
    }
    accl += __shfl_xor(accl, 8, 64);
    accl += __shfl_xor(accl, 16, 64);
    accl += __shfl_xor(accl, 32, 64);
    acch += __shfl_xor(acch, 8, 64);
    acch += __shfl_xor(acch, 16, 64);
    acch += __shfl_xor(acch, 32, 64);
    __shared__ float red[4][16];
    int lane = threadIdx.x & 63, wid = threadIdx.x >> 6;
    if (lane < 8) { red[wid][2 * lane] = accl; red[wid][2 * lane + 1] = acch; }
    __syncthreads();
    if (threadIdx.x < 16) {
        float v = red[0][threadIdx.x] + red[1][threadIdx.x] +
                  red[2][threadIdx.x] + red[3][threadIdx.x];
        atomicAdd(&s[threadIdx.x], v);
    }
}

// ---------------- out = sigmoid((s @ W2) @ w_out + b_out) ----------------
__global__ void k_out(const float* __restrict__ s, const float* __restrict__ W2,
                      const float* __restrict__ w_out,
                      const float* __restrict__ b_out,
                      float* __restrict__ out) {
    int f2 = threadIdx.x;
    float m = 0.f;
    if (f2 < H2) {
        float v = 0.f;
#pragma unroll
        for (int f1 = 0; f1 < H1; f1++) v = fmaf(s[f1], W2[f1 * H2 + f2], v);
        m = v * w_out[f2];
    }
    for (int off = 32; off; off >>= 1) m += __shfl_down(m, off, 64);
    if (f2 == 0) out[0] = 1.f / (1.f + expf(-(m + b_out[0])));
}

extern "C" void kernel_launch(void* const* d_in, const int* in_sizes, int n_in,
                              void* d_out, int out_size, void* d_ws, size_t ws_size,
                              hipStream_t stream) {
    const float* x         = (const float*)d_in[0];
    const float* edge_vals = (const float*)d_in[1];
    const float* W1        = (const float*)d_in[2];
    const float* W2        = (const float*)d_in[3];
    const float* w_out     = (const float*)d_in[4];
    const float* b_out     = (const float*)d_in[5];
    const int*   edge_rows = (const int*)d_in[6];
    const int*   edge_cols = (const int*)d_in[7];
    float* out = (float*)d_out;

    const int N = N_NODES;
    const int E = in_sizes[1];   // 3.2M

    // workspace layout (bytes):
    //   t   (bf16):  [0,          3,200,000)
    //   g2  (bf16):  [3,200,000,  6,400,000)
    //   s   (fp32):  [6,400,000,  6,400,064)
    //   hist (int):  [6,400,064,  6,403,196)  [783]
    //   base (int):  [6,403,200,  6,406,332)  [783]
    //   cursor:      [6,406,400,  6,456,448)  [782*16] u32, 64B-padded
    //   ed (uint2):  [6,456,448, 32,056,448)  E * 8B
    char* ws = (char*)d_ws;
    unsigned short* t    = (unsigned short*)(ws);
    unsigned int*   g2   = (unsigned int*)(ws + 3200000);
    float*          s    = (float*)(ws + 6400000);
    int*            hist = (int*)(ws + 6400064);
    int*            base = (int*)(ws + 6403200);
    unsigned int*   cur  = (unsigned int*)(ws + 6406400);
    uint2*          ed   = (uint2*)(ws + 6456448);

    bool binned = (ws_size >= 32100000);

    k_xw1<<<(N + XW1_ROWS - 1) / XW1_ROWS, 256, 0, stream>>>(x, W1, t, N);

    if (binned) {
        // zero s + hist: [6,400,000, 6,403,200) = 3200 B = 200 float4
        k_zero<<<1, 256, 0, stream>>>((float4*)(ws + 6400000), 200);
        k_hist<<<HIST_BLOCKS, 256, 0, stream>>>(edge_rows, hist, E);
        k_scan<<<1, 1024, 0, stream>>>(hist, base, cur);
        k_scatter<<<(E + CH - 1) / CH, 256, 0, stream>>>(
            edge_rows, edge_cols, edge_vals, cur, ed, E);
        k_gacc<<<NB, 256, 0, stream>>>(ed, base, t, g2, N);
    } else {
        // fallback: zero g2 + s, then atomic edge pass
        k_zero<<<(200004 + 255) / 256, 256, 0, stream>>>(
            (float4*)(ws + 3200000), 200004);
        long long edge_threads = (long long)E * 8;
        k_edge<<<(int)((edge_threads + 255) / 256), 256, 0, stream>>>(
            edge_rows, edge_cols, edge_vals, (const unsigned int*)t, g2, E);
    }

    k_s2<<<1024, 256, 0, stream>>>(edge_cols, edge_vals, g2, s, E);

    k_out<<<1, 64, 0, stream>>>(s, W2, w_out, b_out, out);
}